// Round 8
// baseline (216.115 us; speedup 1.0000x reference)
//
#include <hip/hip_runtime.h>

// MultiHeadAttention: x(4,2048,1024) @ W_attn(1024,3072)+b -> QKV -> causal MHA (16 heads, d=64)
// -> attn @ W_proj(1024,1024)+b. Inputs/outputs FLOAT32; internal compute bf16 MFMA + f32 accum.
//
//   0. convert x (f32) -> xb (bf16)
//   1. transpose+convert W_attn -> Wta (3072x1024 bf16), W_proj -> Wtp (1024x1024 bf16)
//   2. GEMM1: 128x128 tile, 4-slot rotating LDS, 2-deep counted-vmcnt gload_lds pipeline
//   3. flash attention (causal, swapped-MFMA layout), 1 wave = 64 q rows -> Ab (B,T,C) bf16
//   4. GEMM2: same structure, Ab @ Wtp^T + b_proj -> out (f32)

typedef __attribute__((ext_vector_type(8))) __bf16 bf16x8;
typedef __attribute__((ext_vector_type(4))) float f32x4;
typedef __attribute__((ext_vector_type(4))) short s16x4;

__device__ __forceinline__ unsigned short f2bf(float f) {
    unsigned u = __builtin_bit_cast(unsigned, f);
    u += 0x7fffu + ((u >> 16) & 1u);   // RNE
    return (unsigned short)(u >> 16);
}
__device__ __forceinline__ unsigned pack2bf(float a, float b) {
    return (unsigned)f2bf(a) | ((unsigned)f2bf(b) << 16);
}
// async 16B global -> LDS (HW: wave-uniform LDS base + lane*16; global addr per-lane)
__device__ __forceinline__ void gload16(const unsigned short* g, unsigned short* l) {
    __builtin_amdgcn_global_load_lds(
        (const __attribute__((address_space(1))) unsigned int*)g,
        (__attribute__((address_space(3))) unsigned int*)l, 16, 0, 0);
}

// ---------------- f32 -> bf16 elementwise convert (vectorized) ----------------
__global__ void convert_kernel(const float* __restrict__ in, unsigned short* __restrict__ out,
                               long n) {
    long i = ((long)blockIdx.x * blockDim.x + threadIdx.x) * 4;
    if (i >= n) return;
    f32x4 v = *reinterpret_cast<const f32x4*>(&in[i]);
    s16x4 o;
    o[0] = (short)f2bf(v[0]);
    o[1] = (short)f2bf(v[1]);
    o[2] = (short)f2bf(v[2]);
    o[3] = (short)f2bf(v[3]);
    *reinterpret_cast<s16x4*>(&out[i]) = o;
}

// ---------------- 32x32 tiled transpose+convert: Wt[n][k] = bf16(W[k][n]) ----------------
__global__ void transpose_kernel(const float* __restrict__ W,
                                 unsigned short* __restrict__ Wt,
                                 int K, int N) {
    __shared__ float t[32][33];
    const int tid = threadIdx.x;
    const int n0 = blockIdx.x * 32, k0 = blockIdx.y * 32;
    const int row = tid >> 3, c4 = (tid & 7) * 4;
    f32x4 v = *reinterpret_cast<const f32x4*>(&W[(size_t)(k0 + row) * N + n0 + c4]);
    t[row][c4 + 0] = v[0];
    t[row][c4 + 1] = v[1];
    t[row][c4 + 2] = v[2];
    t[row][c4 + 3] = v[3];
    __syncthreads();
    s16x4 o;
    o[0] = (short)f2bf(t[c4 + 0][row]);
    o[1] = (short)f2bf(t[c4 + 1][row]);
    o[2] = (short)f2bf(t[c4 + 2][row]);
    o[3] = (short)f2bf(t[c4 + 3][row]);
    *reinterpret_cast<s16x4*>(&Wt[(size_t)(n0 + row) * K + k0 + c4]) = o;
}

// ====== 128x128 tile MFMA GEMM, 4-slot rotating LDS, 2-deep counted-vmcnt pipeline ======
// Slot s (s=0..3) holds one k-chunk of 32: A[128][32] + B[128][32] (8 KB each), row stride 64 B.
// Swizzle: stored col-byte = logical ^ ((row&3)<<4), applied on the pre-swizzled GLOBAL source
// (gload_lds writes linearly) and inverted on the ds_read address -> balanced banks.
// Phase n: ds_read slot[n&3] (staged 2 phases ago, ensured by phase n-1's vmcnt+barrier);
// issue stage chunk n+2 -> slot[(n+2)&3] (4 gload16/thread); s_waitcnt vmcnt(4) (chunk n+1
// landed, chunk n+2 stays in flight ACROSS the barrier); barrier; 16 MFMA; barrier.
// MODE 0: C = A @ Bt^T + bias -> Cout (f32). MODE 1: scatter QKV bf16 (Q pre-scaled 0.125).
template <int MODE>
__global__ __launch_bounds__(256, 2)
void gemm_kernel(const unsigned short* __restrict__ A,
                 const unsigned short* __restrict__ Bt,
                 const float* __restrict__ bias,
                 float* __restrict__ Cout,
                 unsigned short* __restrict__ Qo,
                 unsigned short* __restrict__ Ko,
                 unsigned short* __restrict__ Vto,
                 int M, int N, int Kd) {
    __shared__ unsigned short As[4][128 * 32];
    __shared__ unsigned short Bs[4][128 * 32];
    const int tid = threadIdx.x;
    const int wave = tid >> 6, lane = tid & 63;
    const int l15 = lane & 15, lhi = lane >> 4;
    const int wm = wave >> 1, wn = wave & 1;
    const int m0 = blockIdx.x * 128, n0 = blockIdx.y * 128;

    f32x4 acc[4][4];
#pragma unroll
    for (int i = 0; i < 4; i++)
#pragma unroll
        for (int j = 0; j < 4; j++) acc[i][j] = f32x4{0.f, 0.f, 0.f, 0.f};

    // staging map: thread -> row r = tid>>2 (and r+64), 16B chunk (tid&3); source col
    // pre-swizzled: ((tid&3) ^ (r&3)) * 8 elems. LDS dest = slot + tid*16B (+4096B upper).
    const int r0 = tid >> 2;
    const int cstage = (((tid & 3) ^ (r0 & 3)) << 3);
    const unsigned short* Ap = &A[(size_t)(m0 + r0) * Kd + cstage];
    const unsigned short* Bp = &Bt[(size_t)(n0 + r0) * Kd + cstage];
    const size_t K64 = (size_t)64 * Kd;
    // ds_read col (elems): (lhi*8) ^ ((l15&3)<<3)  [row&3 == l15&3 for frag rows]
    const int csw = (lhi * 8) ^ ((l15 & 3) << 3);

#define STAGE(sl, k0)                                   \
    do {                                                \
        gload16(Ap + (k0), &As[sl][tid * 8]);           \
        gload16(Ap + K64 + (k0), &As[sl][2048 + tid * 8]); \
        gload16(Bp + (k0), &Bs[sl][tid * 8]);           \
        gload16(Bp + K64 + (k0), &Bs[sl][2048 + tid * 8]); \
    } while (0)

#define VW4 asm volatile("s_waitcnt vmcnt(4)" ::: "memory")
#define VW0 asm volatile("s_waitcnt vmcnt(0)" ::: "memory")

#define PH(sl, sg, kc, WAITM)                                                              \
    do {                                                                                   \
        bf16x8 av_[4], bv_[4];                                                             \
        _Pragma("unroll") for (int i_ = 0; i_ < 4; i_++) {                                 \
            av_[i_] = *reinterpret_cast<const bf16x8*>(                                    \
                &As[sl][(wm * 64 + i_ * 16 + l15) * 32 + csw]);                            \
            bv_[i_] = *reinterpret_cast<const bf16x8*>(                                    \
                &Bs[sl][(wn * 64 + i_ * 16 + l15) * 32 + csw]);                            \
        }                                                                                  \
        if (sg) STAGE((sl + 2) & 3, (kc) * 32);                                            \
        WAITM;                                                                             \
        __builtin_amdgcn_s_barrier();                                                      \
        __builtin_amdgcn_s_setprio(1);                                                     \
        _Pragma("unroll") for (int i_ = 0; i_ < 4; i_++)                                   \
            _Pragma("unroll") for (int j_ = 0; j_ < 4; j_++)                               \
                acc[i_][j_] = __builtin_amdgcn_mfma_f32_16x16x32_bf16(av_[i_], bv_[j_],    \
                                                                      acc[i_][j_], 0, 0, 0); \
        __builtin_amdgcn_s_setprio(0);                                                     \
        __builtin_amdgcn_s_barrier();                                                      \
    } while (0)

    // prologue: chunks 0,1 staged; vmcnt(4) -> chunk 0 landed, chunk 1 may fly
    STAGE(0, 0);
    STAGE(1, 32);
    VW4;
    __builtin_amdgcn_s_barrier();

    const int NPH = Kd >> 5;              // k-chunks of 32; multiple of 4
    for (int it = 0; it < (NPH >> 2) - 1; ++it) {
        const int kc = it * 4;
        PH(0, true, kc + 2, VW4);
        PH(1, true, kc + 3, VW4);
        PH(2, true, kc + 4, VW4);
        PH(3, true, kc + 5, VW4);
    }
    PH(0, true, NPH - 2, VW4);
    PH(1, true, NPH - 1, VW4);
    PH(2, false, 0, VW0);
    PH(3, false, 0, VW0);
#undef PH
#undef STAGE
#undef VW4
#undef VW0

    // epilogue: D[row=(lane>>4)*4+r][col=lane&15] per 16x16 fragment
#pragma unroll
    for (int j = 0; j < 4; j++) {
        const int col = n0 + wn * 64 + j * 16 + l15;
        const float bv = bias[col];
#pragma unroll
        for (int i = 0; i < 4; i++) {
            const int rbase = m0 + wm * 64 + i * 16 + lhi * 4;
#pragma unroll
            for (int r = 0; r < 4; r++) {
                const int row = rbase + r;
                const float oval = acc[i][j][r] + bv;
                if (MODE == 0) {
                    Cout[(size_t)row * N + col] = oval;
                } else {
                    const int sel = col >> 10, c1 = col & 1023;
                    const int h = c1 >> 6, d = c1 & 63;
                    const int b = row >> 11, t = row & 2047;
                    if (sel == 0)
                        Qo[(((size_t)(b * 16 + h)) * 2048 + t) * 64 + d] = f2bf(oval * 0.125f);
                    else if (sel == 1)
                        Ko[(((size_t)(b * 16 + h)) * 2048 + t) * 64 + d] = f2bf(oval);
                    else
                        Vto[(((size_t)(b * 16 + h)) * 64 + d) * 2048 + t] = f2bf(oval);
                }
            }
        }
    }
}

// ---------------- causal flash attention, swapped-MFMA layout ----------------
// 1 wave = 64 q rows (4 q-frags); block = 4 waves = 256 q rows; grid = 512 (head = bid&63).
__global__ __launch_bounds__(256, 2)
void attn_kernel(const unsigned short* __restrict__ Q,
                 const unsigned short* __restrict__ Kg,
                 const unsigned short* __restrict__ Vt,
                 unsigned short* __restrict__ Aout) {
    __shared__ unsigned int Pl[4][16 * 36];     // per-wave P^T tile: [q=16][k=64] bf16, 144B rows
    const int tid = threadIdx.x, wave = tid >> 6, lane = tid & 63;
    const int l15 = lane & 15, lhi = lane >> 4;
    const int bid = blockIdx.x;
    const int head = bid & 63;
    const int j = bid >> 6;
    const int qb = (j < 4) ? j : (11 - j);       // complement pairing: qb(j)+qb(j+4)=7
    const int q0w = qb * 256 + wave * 64;
    const unsigned short* Qh = Q + (size_t)head * (2048 * 64);
    const unsigned short* Kh = Kg + (size_t)head * (2048 * 64);
    const unsigned short* Vh = Vt + (size_t)head * (64 * 2048);
    unsigned int* P = &Pl[wave][0];

    bf16x8 qfr[4][2];
#pragma unroll
    for (int qf = 0; qf < 4; qf++)
#pragma unroll
        for (int dh = 0; dh < 2; dh++)
            qfr[qf][dh] = *reinterpret_cast<const bf16x8*>(
                &Qh[(size_t)(q0w + qf * 16 + l15) * 64 + dh * 32 + lhi * 8]);

    f32x4 o[4][4];   // [df][qf], O^T[d=df*16+lhi*4+r][q=qf*16+l15]
#pragma unroll
    for (int df = 0; df < 4; df++)
#pragma unroll
        for (int qf = 0; qf < 4; qf++) o[df][qf] = f32x4{0.f, 0.f, 0.f, 0.f};
    float m[4] = {-1e30f, -1e30f, -1e30f, -1e30f};
    float l[4] = {0.f, 0.f, 0.f, 0.f};

    const int ntiles = (q0w >> 6) + 1;
    for (int t = 0; t < ntiles; ++t) {
        const int kt = t * 64;
        const bool masked = (t == ntiles - 1);
        bf16x8 kfr[4][2], vfr[4][2];
#pragma unroll
        for (int kf = 0; kf < 4; kf++)
#pragma unroll
            for (int dh = 0; dh < 2; dh++)
                kfr[kf][dh] = *reinterpret_cast<const bf16x8*>(
                    &Kh[(size_t)(kt + kf * 16 + l15) * 64 + dh * 32 + lhi * 8]);
#pragma unroll
        for (int df = 0; df < 4; df++)
#pragma unroll
            for (int kc = 0; kc < 2; kc++)
                vfr[df][kc] = *reinterpret_cast<const bf16x8*>(
                    &Vh[(size_t)(df * 16 + l15) * 2048 + kt + kc * 32 + lhi * 8]);

#pragma unroll
        for (int qf = 0; qf < 4; qf++) {
            f32x4 s[4];
#pragma unroll
            for (int kf = 0; kf < 4; kf++) {
                s[kf] = __builtin_amdgcn_mfma_f32_16x16x32_bf16(kfr[kf][0], qfr[qf][0],
                                                                f32x4{0.f, 0.f, 0.f, 0.f}, 0, 0, 0);
                s[kf] = __builtin_amdgcn_mfma_f32_16x16x32_bf16(kfr[kf][1], qfr[qf][1], s[kf], 0, 0, 0);
            }
            if (masked) {
#pragma unroll
                for (int kf = 0; kf < 4; kf++)
#pragma unroll
                    for (int r = 0; r < 4; r++)
                        if (kf * 16 + lhi * 4 + r > qf * 16 + l15) s[kf][r] = -1e30f;
            }
            float tm = s[0][0];
#pragma unroll
            for (int kf = 0; kf < 4; kf++)
#pragma unroll
                for (int r = 0; r < 4; r++) tm = fmaxf(tm, s[kf][r]);
            tm = fmaxf(tm, __shfl_xor(tm, 16));
            tm = fmaxf(tm, __shfl_xor(tm, 32));
            const float mn = fmaxf(m[qf], tm);
            const float corr = __expf(m[qf] - mn);
            m[qf] = mn;
            float rs = 0.f;
#pragma unroll
            for (int kf = 0; kf < 4; kf++)
#pragma unroll
                for (int r = 0; r < 4; r++) {
                    const float p = __expf(s[kf][r] - mn);
                    s[kf][r] = p;
                    rs += p;
                }
            rs += __shfl_xor(rs, 16);
            rs += __shfl_xor(rs, 32);
            l[qf] = l[qf] * corr + rs;
#pragma unroll
            for (int df = 0; df < 4; df++)
#pragma unroll
                for (int r = 0; r < 4; r++) o[df][qf][r] *= corr;

#pragma unroll
            for (int kf = 0; kf < 4; kf++) {
                P[l15 * 36 + kf * 8 + lhi * 2 + 0] = pack2bf(s[kf][0], s[kf][1]);
                P[l15 * 36 + kf * 8 + lhi * 2 + 1] = pack2bf(s[kf][2], s[kf][3]);
            }
            asm volatile("s_waitcnt lgkmcnt(0)" ::: "memory");
            bf16x8 pb0 = *reinterpret_cast<const bf16x8*>(&P[l15 * 36 + 0 * 16 + lhi * 4]);
            bf16x8 pb1 = *reinterpret_cast<const bf16x8*>(&P[l15 * 36 + 1 * 16 + lhi * 4]);
#pragma unroll
            for (int df = 0; df < 4; df++) {
                o[df][qf] = __builtin_amdgcn_mfma_f32_16x16x32_bf16(vfr[df][0], pb0, o[df][qf], 0, 0, 0);
                o[df][qf] = __builtin_amdgcn_mfma_f32_16x16x32_bf16(vfr[df][1], pb1, o[df][qf], 0, 0, 0);
            }
        }
    }

    const int b = head >> 4, h = head & 15;
#pragma unroll
    for (int qf = 0; qf < 4; qf++) {
        const float inv = 1.0f / l[qf];
        unsigned short* op = Aout + ((size_t)(b * 2048 + q0w + qf * 16 + l15)) * 1024 + h * 64;
#pragma unroll
        for (int df = 0; df < 4; df++) {
            *reinterpret_cast<unsigned*>(&op[df * 16 + lhi * 4]) =
                pack2bf(o[df][qf][0] * inv, o[df][qf][1] * inv);
            *reinterpret_cast<unsigned*>(&op[df * 16 + lhi * 4 + 2]) =
                pack2bf(o[df][qf][2] * inv, o[df][qf][3] * inv);
        }
    }
}

extern "C" void kernel_launch(void* const* d_in, const int* in_sizes, int n_in,
                              void* d_out, int out_size, void* d_ws, size_t ws_size,
                              hipStream_t stream) {
    const float* x     = (const float*)d_in[0];
    const float* Wattn = (const float*)d_in[1];
    const float* battn = (const float*)d_in[2];
    const float* Wproj = (const float*)d_in[3];
    const float* bproj = (const float*)d_in[4];
    float* out = (float*)d_out;

    unsigned short* ws = (unsigned short*)d_ws;
    const size_t HS = (size_t)4 * 16 * 2048 * 64;
    unsigned short* Qb  = ws;
    unsigned short* Kb  = Qb + HS;
    unsigned short* Vtb = Kb + HS;
    unsigned short* Ab  = Vtb + HS;
    unsigned short* Wta = Ab + HS;
    unsigned short* Wtp = Wta + (size_t)3072 * 1024;
    unsigned short* xb  = Wtp + (size_t)1024 * 1024;

    convert_kernel<<<8192, 256, 0, stream>>>(x, xb, (long)HS);
    transpose_kernel<<<dim3(96, 32), 256, 0, stream>>>(Wattn, Wta, 1024, 3072);
    transpose_kernel<<<dim3(32, 32), 256, 0, stream>>>(Wproj, Wtp, 1024, 1024);
    gemm_kernel<1><<<dim3(64, 24), 256, 0, stream>>>(xb, Wta, battn, nullptr, Qb, Kb, Vtb,
                                                     8192, 3072, 1024);
    attn_kernel<<<512, 256, 0, stream>>>(Qb, Kb, Vtb, Ab);
    gemm_kernel<0><<<dim3(64, 8), 256, 0, stream>>>(Ab, Wtp, bproj, out, nullptr, nullptr, nullptr,
                                                    8192, 1024, 1024);
}

// Round 9
// 203.931 us; speedup vs baseline: 1.0597x; 1.0597x over previous
//
#include <hip/hip_runtime.h>

// MultiHeadAttention: x(4,2048,1024) @ W_attn(1024,3072)+b -> QKV -> causal MHA (16 heads, d=64)
// -> attn @ W_proj(1024,1024)+b. Inputs/outputs FLOAT32; internal compute bf16 MFMA + f32 accum.
//
//   0. convert x (f32) -> xb (bf16)
//   1. transpose+convert W_attn -> Wta (3072x1024 bf16), W_proj -> Wtp (1024x1024 bf16)
//   2. GEMM1: 128x128 BK=64 single-buffer gload_lds + XOR swizzle + XCD-supertile block remap
//   3. flash attention (causal, swapped-MFMA layout), 1 wave = 64 q rows -> Ab (B,T,C) bf16
//   4. GEMM2: same structure -> out (f32)

typedef __attribute__((ext_vector_type(8))) __bf16 bf16x8;
typedef __attribute__((ext_vector_type(4))) float f32x4;
typedef __attribute__((ext_vector_type(4))) short s16x4;

__device__ __forceinline__ unsigned short f2bf(float f) {
    unsigned u = __builtin_bit_cast(unsigned, f);
    u += 0x7fffu + ((u >> 16) & 1u);   // RNE
    return (unsigned short)(u >> 16);
}
__device__ __forceinline__ unsigned pack2bf(float a, float b) {
    return (unsigned)f2bf(a) | ((unsigned)f2bf(b) << 16);
}
// async 16B global -> LDS (HW: wave-uniform LDS base + lane*16; global addr per-lane)
__device__ __forceinline__ void gload16(const unsigned short* g, unsigned short* l) {
    __builtin_amdgcn_global_load_lds(
        (const __attribute__((address_space(1))) unsigned int*)g,
        (__attribute__((address_space(3))) unsigned int*)l, 16, 0, 0);
}

// ---------------- f32 -> bf16 elementwise convert (vectorized) ----------------
__global__ void convert_kernel(const float* __restrict__ in, unsigned short* __restrict__ out,
                               long n) {
    long i = ((long)blockIdx.x * blockDim.x + threadIdx.x) * 4;
    if (i >= n) return;
    f32x4 v = *reinterpret_cast<const f32x4*>(&in[i]);
    s16x4 o;
    o[0] = (short)f2bf(v[0]);
    o[1] = (short)f2bf(v[1]);
    o[2] = (short)f2bf(v[2]);
    o[3] = (short)f2bf(v[3]);
    *reinterpret_cast<s16x4*>(&out[i]) = o;
}

// ---------------- 32x32 tiled transpose+convert: Wt[n][k] = bf16(W[k][n]) ----------------
__global__ void transpose_kernel(const float* __restrict__ W,
                                 unsigned short* __restrict__ Wt,
                                 int K, int N) {
    __shared__ float t[32][33];
    const int tid = threadIdx.x;
    const int n0 = blockIdx.x * 32, k0 = blockIdx.y * 32;
    const int row = tid >> 3, c4 = (tid & 7) * 4;
    f32x4 v = *reinterpret_cast<const f32x4*>(&W[(size_t)(k0 + row) * N + n0 + c4]);
    t[row][c4 + 0] = v[0];
    t[row][c4 + 1] = v[1];
    t[row][c4 + 2] = v[2];
    t[row][c4 + 3] = v[3];
    __syncthreads();
    s16x4 o;
    o[0] = (short)f2bf(t[c4 + 0][row]);
    o[1] = (short)f2bf(t[c4 + 1][row]);
    o[2] = (short)f2bf(t[c4 + 2][row]);
    o[3] = (short)f2bf(t[c4 + 3][row]);
    *reinterpret_cast<s16x4*>(&Wt[(size_t)(n0 + row) * K + k0 + c4]) = o;
}

// ====== 128x128 tile MFMA GEMM, BK=64 single-buffer gload_lds, XOR-swizzled LDS ======
// Block remap (1D grid): dispatch slot s -> XCD (s&7) [HW round-robin heuristic]; within an
// XCD, blocks walk 4bm x SN-bn SUPERTILES (A 4x256KB + B SNx256KB fits the 4MB per-XCD L2),
// so panel re-fetches hit L2 instead of L3. MODE 1 (GEMM1): 64bm x 24bn, SN=6.
// MODE 0 (GEMM2): 64bm x 8bn, SN=4. Pure locality reorder — bijective, correctness-neutral.
// LDS swizzle: stored col-byte = logical ^ ((row&7)<<4), pre-swizzled global source +
// inverted ds_read address -> conflict-free b128 reads.
template <int MODE>
__global__ __launch_bounds__(256, 2)
void gemm_kernel(const unsigned short* __restrict__ A,
                 const unsigned short* __restrict__ Bt,
                 const float* __restrict__ bias,
                 float* __restrict__ Cout,
                 unsigned short* __restrict__ Qo,
                 unsigned short* __restrict__ Ko,
                 unsigned short* __restrict__ Vto,
                 int M, int N, int Kd) {
    __shared__ unsigned short As[128 * 64];
    __shared__ unsigned short Bs[128 * 64];
    const int tid = threadIdx.x;
    const int wave = tid >> 6, lane = tid & 63;
    const int l15 = lane & 15, lhi = lane >> 4;
    const int wm = wave >> 1, wn = wave & 1;

    // supertile/XCD remap
    const int SN = (MODE == 1) ? 6 : 4;
    const int bid = blockIdx.x;
    const int xcd = bid & 7, t = bid >> 3;
    const int t2 = t % (4 * SN), st = t / (4 * SN);
    const int bm = xcd * 8 + ((st & 1) << 2) + (t2 & 3);
    const int bn = (st >> 1) * SN + (t2 >> 2);
    const int m0 = bm * 128, n0 = bn * 128;

    f32x4 acc[4][4];
#pragma unroll
    for (int i = 0; i < 4; i++)
#pragma unroll
        for (int j = 0; j < 4; j++) acc[i][j] = f32x4{0.f, 0.f, 0.f, 0.f};

    // staging: thread -> (row = tid>>3 in 4 blocks of 32 rows, 16B chunk (tid&7) of the row)
    // source col pre-swizzled: cswz = ((tid&7) ^ (row&7)) * 8 elems
    const int r0 = tid >> 3;
    const int cswz = (((tid & 7) ^ (r0 & 7)) << 3);
    const unsigned short* Ap = &A[(size_t)(m0 + r0) * Kd + cswz];
    const unsigned short* Bp = &Bt[(size_t)(n0 + r0) * Kd + cswz];
    const size_t K32 = (size_t)32 * Kd;
    // ds_read col offset (elems): (ks*32 + lhi*8) ^ ((l15&7)<<3)
    const int csw0 = (lhi * 8) ^ ((l15 & 7) << 3);

    for (int k0 = 0; k0 < Kd; k0 += 64) {
#pragma unroll
        for (int blk = 0; blk < 4; blk++) {
            gload16(Ap + blk * K32 + k0, &As[blk * 2048 + tid * 8]);
            gload16(Bp + blk * K32 + k0, &Bs[blk * 2048 + tid * 8]);
        }
        __syncthreads();   // drains vmcnt(0): buffer ready

        bf16x8 av[2][4], bv[2][4];
#pragma unroll
        for (int ks = 0; ks < 2; ks++)
#pragma unroll
            for (int i = 0; i < 4; i++) {
                av[ks][i] = *reinterpret_cast<const bf16x8*>(
                    &As[(wm * 64 + i * 16 + l15) * 64 + (ks * 32 ^ csw0)]);
                bv[ks][i] = *reinterpret_cast<const bf16x8*>(
                    &Bs[(wn * 64 + i * 16 + l15) * 64 + (ks * 32 ^ csw0)]);
            }
#pragma unroll
        for (int ks = 0; ks < 2; ks++)
#pragma unroll
            for (int i = 0; i < 4; i++)
#pragma unroll
                for (int j = 0; j < 4; j++)
                    acc[i][j] = __builtin_amdgcn_mfma_f32_16x16x32_bf16(av[ks][i], bv[ks][j],
                                                                        acc[i][j], 0, 0, 0);
        __syncthreads();
    }

    // epilogue: D[row=(lane>>4)*4+r][col=lane&15] per 16x16 fragment
#pragma unroll
    for (int j = 0; j < 4; j++) {
        const int col = n0 + wn * 64 + j * 16 + l15;
        const float bv = bias[col];
#pragma unroll
        for (int i = 0; i < 4; i++) {
            const int rbase = m0 + wm * 64 + i * 16 + lhi * 4;
#pragma unroll
            for (int r = 0; r < 4; r++) {
                const int row = rbase + r;
                const float oval = acc[i][j][r] + bv;
                if (MODE == 0) {
                    Cout[(size_t)row * N + col] = oval;
                } else {
                    const int sel = col >> 10, c1 = col & 1023;
                    const int h = c1 >> 6, d = c1 & 63;
                    const int b = row >> 11, t2_ = row & 2047;
                    if (sel == 0)
                        Qo[(((size_t)(b * 16 + h)) * 2048 + t2_) * 64 + d] = f2bf(oval * 0.125f);
                    else if (sel == 1)
                        Ko[(((size_t)(b * 16 + h)) * 2048 + t2_) * 64 + d] = f2bf(oval);
                    else
                        Vto[(((size_t)(b * 16 + h)) * 64 + d) * 2048 + t2_] = f2bf(oval);
                }
            }
        }
    }
}

// ---------------- causal flash attention, swapped-MFMA layout ----------------
// 1 wave = 64 q rows (4 q-frags); block = 4 waves = 256 q rows; grid = 512 (head = bid&63).
__global__ __launch_bounds__(256, 2)
void attn_kernel(const unsigned short* __restrict__ Q,
                 const unsigned short* __restrict__ Kg,
                 const unsigned short* __restrict__ Vt,
                 unsigned short* __restrict__ Aout) {
    __shared__ unsigned int Pl[4][16 * 36];     // per-wave P^T tile: [q=16][k=64] bf16, 144B rows
    const int tid = threadIdx.x, wave = tid >> 6, lane = tid & 63;
    const int l15 = lane & 15, lhi = lane >> 4;
    const int bid = blockIdx.x;
    const int head = bid & 63;
    const int j = bid >> 6;
    const int qb = (j < 4) ? j : (11 - j);       // complement pairing: qb(j)+qb(j+4)=7
    const int q0w = qb * 256 + wave * 64;
    const unsigned short* Qh = Q + (size_t)head * (2048 * 64);
    const unsigned short* Kh = Kg + (size_t)head * (2048 * 64);
    const unsigned short* Vh = Vt + (size_t)head * (64 * 2048);
    unsigned int* P = &Pl[wave][0];

    bf16x8 qfr[4][2];
#pragma unroll
    for (int qf = 0; qf < 4; qf++)
#pragma unroll
        for (int dh = 0; dh < 2; dh++)
            qfr[qf][dh] = *reinterpret_cast<const bf16x8*>(
                &Qh[(size_t)(q0w + qf * 16 + l15) * 64 + dh * 32 + lhi * 8]);

    f32x4 o[4][4];   // [df][qf], O^T[d=df*16+lhi*4+r][q=qf*16+l15]
#pragma unroll
    for (int df = 0; df < 4; df++)
#pragma unroll
        for (int qf = 0; qf < 4; qf++) o[df][qf] = f32x4{0.f, 0.f, 0.f, 0.f};
    float m[4] = {-1e30f, -1e30f, -1e30f, -1e30f};
    float l[4] = {0.f, 0.f, 0.f, 0.f};

    const int ntiles = (q0w >> 6) + 1;
    for (int t = 0; t < ntiles; ++t) {
        const int kt = t * 64;
        const bool masked = (t == ntiles - 1);
        bf16x8 kfr[4][2], vfr[4][2];
#pragma unroll
        for (int kf = 0; kf < 4; kf++)
#pragma unroll
            for (int dh = 0; dh < 2; dh++)
                kfr[kf][dh] = *reinterpret_cast<const bf16x8*>(
                    &Kh[(size_t)(kt + kf * 16 + l15) * 64 + dh * 32 + lhi * 8]);
#pragma unroll
        for (int df = 0; df < 4; df++)
#pragma unroll
            for (int kc = 0; kc < 2; kc++)
                vfr[df][kc] = *reinterpret_cast<const bf16x8*>(
                    &Vh[(size_t)(df * 16 + l15) * 2048 + kt + kc * 32 + lhi * 8]);

#pragma unroll
        for (int qf = 0; qf < 4; qf++) {
            f32x4 s[4];
#pragma unroll
            for (int kf = 0; kf < 4; kf++) {
                s[kf] = __builtin_amdgcn_mfma_f32_16x16x32_bf16(kfr[kf][0], qfr[qf][0],
                                                                f32x4{0.f, 0.f, 0.f, 0.f}, 0, 0, 0);
                s[kf] = __builtin_amdgcn_mfma_f32_16x16x32_bf16(kfr[kf][1], qfr[qf][1], s[kf], 0, 0, 0);
            }
            if (masked) {
#pragma unroll
                for (int kf = 0; kf < 4; kf++)
#pragma unroll
                    for (int r = 0; r < 4; r++)
                        if (kf * 16 + lhi * 4 + r > qf * 16 + l15) s[kf][r] = -1e30f;
            }
            float tm = s[0][0];
#pragma unroll
            for (int kf = 0; kf < 4; kf++)
#pragma unroll
                for (int r = 0; r < 4; r++) tm = fmaxf(tm, s[kf][r]);
            tm = fmaxf(tm, __shfl_xor(tm, 16));
            tm = fmaxf(tm, __shfl_xor(tm, 32));
            const float mn = fmaxf(m[qf], tm);
            const float corr = __expf(m[qf] - mn);
            m[qf] = mn;
            float rs = 0.f;
#pragma unroll
            for (int kf = 0; kf < 4; kf++)
#pragma unroll
                for (int r = 0; r < 4; r++) {
                    const float p = __expf(s[kf][r] - mn);
                    s[kf][r] = p;
                    rs += p;
                }
            rs += __shfl_xor(rs, 16);
            rs += __shfl_xor(rs, 32);
            l[qf] = l[qf] * corr + rs;
#pragma unroll
            for (int df = 0; df < 4; df++)
#pragma unroll
                for (int r = 0; r < 4; r++) o[df][qf][r] *= corr;

#pragma unroll
            for (int kf = 0; kf < 4; kf++) {
                P[l15 * 36 + kf * 8 + lhi * 2 + 0] = pack2bf(s[kf][0], s[kf][1]);
                P[l15 * 36 + kf * 8 + lhi * 2 + 1] = pack2bf(s[kf][2], s[kf][3]);
            }
            asm volatile("s_waitcnt lgkmcnt(0)" ::: "memory");
            bf16x8 pb0 = *reinterpret_cast<const bf16x8*>(&P[l15 * 36 + 0 * 16 + lhi * 4]);
            bf16x8 pb1 = *reinterpret_cast<const bf16x8*>(&P[l15 * 36 + 1 * 16 + lhi * 4]);
#pragma unroll
            for (int df = 0; df < 4; df++) {
                o[df][qf] = __builtin_amdgcn_mfma_f32_16x16x32_bf16(vfr[df][0], pb0, o[df][qf], 0, 0, 0);
                o[df][qf] = __builtin_amdgcn_mfma_f32_16x16x32_bf16(vfr[df][1], pb1, o[df][qf], 0, 0, 0);
            }
        }
    }

    const int b = head >> 4, h = head & 15;
#pragma unroll
    for (int qf = 0; qf < 4; qf++) {
        const float inv = 1.0f / l[qf];
        unsigned short* op = Aout + ((size_t)(b * 2048 + q0w + qf * 16 + l15)) * 1024 + h * 64;
#pragma unroll
        for (int df = 0; df < 4; df++) {
            *reinterpret_cast<unsigned*>(&op[df * 16 + lhi * 4]) =
                pack2bf(o[df][qf][0] * inv, o[df][qf][1] * inv);
            *reinterpret_cast<unsigned*>(&op[df * 16 + lhi * 4 + 2]) =
                pack2bf(o[df][qf][2] * inv, o[df][qf][3] * inv);
        }
    }
}

extern "C" void kernel_launch(void* const* d_in, const int* in_sizes, int n_in,
                              void* d_out, int out_size, void* d_ws, size_t ws_size,
                              hipStream_t stream) {
    const float* x     = (const float*)d_in[0];
    const float* Wattn = (const float*)d_in[1];
    const float* battn = (const float*)d_in[2];
    const float* Wproj = (const float*)d_in[3];
    const float* bproj = (const float*)d_in[4];
    float* out = (float*)d_out;

    unsigned short* ws = (unsigned short*)d_ws;
    const size_t HS = (size_t)4 * 16 * 2048 * 64;
    unsigned short* Qb  = ws;
    unsigned short* Kb  = Qb + HS;
    unsigned short* Vtb = Kb + HS;
    unsigned short* Ab  = Vtb + HS;
    unsigned short* Wta = Ab + HS;
    unsigned short* Wtp = Wta + (size_t)3072 * 1024;
    unsigned short* xb  = Wtp + (size_t)1024 * 1024;

    convert_kernel<<<8192, 256, 0, stream>>>(x, xb, (long)HS);
    transpose_kernel<<<dim3(96, 32), 256, 0, stream>>>(Wattn, Wta, 1024, 3072);
    transpose_kernel<<<dim3(32, 32), 256, 0, stream>>>(Wproj, Wtp, 1024, 1024);
    gemm_kernel<1><<<1536, 256, 0, stream>>>(xb, Wta, battn, nullptr, Qb, Kb, Vtb,
                                             8192, 3072, 1024);
    attn_kernel<<<512, 256, 0, stream>>>(Qb, Kb, Vtb, Ab);
    gemm_kernel<0><<<512, 256, 0, stream>>>(Ab, Wtp, bproj, out, nullptr, nullptr, nullptr,
                                            8192, 1024, 1024);
}